// Round 4
// baseline (92.006 us; speedup 1.0000x reference)
//
#include <hip/hip_runtime.h>
#include <hip/hip_bf16.h>

#define N_ROWS 4096
#define TWO_N  8192
#define D      256
#define DB     512                     // bytes per z row

// z is pre-scaled by sqrt(log2(e)/T) so sim' = sim * log2(e)/0.07 comes out of
// the MFMA ready for exp2. pos/T = sim' * ln2.
#define K_SQRT_SCALE 4.5398159980773926f   // sqrt(1.4426950408889634/0.07)
#define K_LN2        0.6931471805599453f

// simexp tiling: block = 256 rows x 64 cols, K split into 8 slices of 32.
#define ROWS_PER_WAVE 64               // 4 strips of 16
#define BLOCK_ROWS    256
#define COLS_PER_BLK  64
#define KSLICE        32
#define NKT           8                // 256 / 32
#define ROW_TILES     (TWO_N / BLOCK_ROWS)   // 32
#define COL_TILES     (TWO_N / COLS_PER_BLK) // 128
#define NBLOCKS       (ROW_TILES * COL_TILES) // 4096

typedef __attribute__((ext_vector_type(8))) short short8;
typedef __attribute__((ext_vector_type(4))) float f32x4;

static __device__ inline unsigned short f2bf(float x) {
    __hip_bfloat16 h = __float2bfloat16(x);
    return __builtin_bit_cast(unsigned short, h);
}

// One wave per row: L2-normalize, scale, write bf16 row. Also zero S.
__global__ __launch_bounds__(256) void normalize_kernel(
        const float* __restrict__ emb_i, const float* __restrict__ emb_j,
        unsigned short* __restrict__ z, float* __restrict__ S) {
    const int gtid = blockIdx.x * 256 + threadIdx.x;
    if (gtid < TWO_N) S[gtid] = 0.0f;

    const int row  = gtid >> 6;        // one wave per row
    const int lane = threadIdx.x & 63;
    if (row >= TWO_N) return;

    const float* src = (row < N_ROWS) ? emb_i + (size_t)row * D
                                      : emb_j + (size_t)(row - N_ROWS) * D;
    float4 v = reinterpret_cast<const float4*>(src)[lane];
    float ss = v.x * v.x + v.y * v.y + v.z * v.z + v.w * v.w;
    #pragma unroll
    for (int m = 1; m < 64; m <<= 1) ss += __shfl_xor(ss, m);
    const float rn = K_SQRT_SCALE / fmaxf(sqrtf(ss), 1e-12f);

    ushort4 o;
    o.x = f2bf(v.x * rn);
    o.y = f2bf(v.y * rn);
    o.z = f2bf(v.z * rn);
    o.w = f2bf(v.w * rn);
    reinterpret_cast<ushort4*>(z + (size_t)row * D)[lane] = o;
}

// K-split flash GEMM: acc[4 strips][4 col-subtiles] persists across 8 K-slices.
// B k-slice staged in LDS (4 KB dbuf), A fragments reloaded per slice (32 regs).
__global__ __launch_bounds__(256, 4) void simexp_kernel(
        const unsigned short* __restrict__ z,
        float* __restrict__ S, float* __restrict__ posv) {
    __shared__ unsigned short lds[2][COLS_PER_BLK * KSLICE];   // 2 x 4 KB

    const int tid  = threadIdx.x;
    const int lane = tid & 63;
    const int wave = tid >> 6;
    const int lmod = lane & 15;
    const int lhi  = lane >> 4;

    // XCD-aware swizzle: consecutive blocks on one XCD share the A row-panel.
    const int wgid    = (blockIdx.x & 7) * (NBLOCKS / 8) + (blockIdx.x >> 3);
    const int rowtile = wgid >> 7;            // / COL_TILES
    const int coltile = wgid & (COL_TILES - 1);
    const int R = rowtile * BLOCK_ROWS + wave * ROWS_PER_WAVE;
    const int C = coltile * COLS_PER_BLK;

    const char* zb = (const char*)z;

    // Staging: thread stages 16B. LDS byte L=tid*16 -> col=tid>>2, kb=(tid&3)*16.
    const size_t ssrc = (size_t)(C + (tid >> 2)) * DB + (size_t)((tid & 3) * 16);
    const int    sdst = tid * 16;

    f32x4 acc[4][4];   // [strip][cs]
    #pragma unroll
    for (int s = 0; s < 4; ++s)
        #pragma unroll
        for (int c = 0; c < 4; ++c) acc[s][c] = (f32x4){0.f, 0.f, 0.f, 0.f};

    short8 aA[4], aB[4];

#define STAGE_B(kt, buf)                                                        \
    __builtin_amdgcn_global_load_lds(                                           \
        (const __attribute__((address_space(1))) unsigned int*)(zb + ssrc + (kt) * 64), \
        (__attribute__((address_space(3))) unsigned int*)((char*)&lds[buf][0] + sdst),  \
        16, 0, 0)

#define LOAD_A(kt, dst)                                                         \
    _Pragma("unroll")                                                           \
    for (int s = 0; s < 4; ++s)                                                 \
        dst[s] = *reinterpret_cast<const short8*>(                              \
            zb + (size_t)(R + s * 16 + lmod) * DB + (kt) * 64 + lhi * 16)

#define COMPUTE(buf, a)                                                         \
    do {                                                                        \
        const char* base_ = (const char*)&lds[buf][0] + lhi * 16;               \
        __builtin_amdgcn_s_setprio(1);                                          \
        _Pragma("unroll")                                                       \
        for (int cs = 0; cs < 4; ++cs) {                                        \
            short8 b_ = *reinterpret_cast<const short8*>(base_ + (cs * 16 + lmod) * 64); \
            _Pragma("unroll")                                                   \
            for (int s = 0; s < 4; ++s)                                         \
                acc[s][cs] = __builtin_amdgcn_mfma_f32_16x16x32_bf16(a[s], b_, acc[s][cs], 0, 0, 0); \
        }                                                                       \
        __builtin_amdgcn_s_setprio(0);                                          \
    } while (0)

    STAGE_B(0, 0);
    LOAD_A(0, aA);
    __syncthreads();

    for (int t = 0; t < 4; ++t) {          // dynamic loop: kt = 2t (buf0), 2t+1 (buf1)
        STAGE_B(2 * t + 1, 1);             // prefetch next slice
        LOAD_A(2 * t + 1, aB);
        COMPUTE(0, aA);
        __syncthreads();                   // drains vmcnt -> buf1 + aB ready

        if (t < 3) {
            STAGE_B(2 * t + 2, 0);
            LOAD_A(2 * t + 2, aA);
        }
        COMPUTE(1, aB);
        __syncthreads();
    }

#undef STAGE_B
#undef LOAD_A
#undef COMPUTE

    // ---- epilogue: exp2, diagonal/positive handling, row sums ----
    float sums[4][4];
    #pragma unroll
    for (int s = 0; s < 4; ++s)
        #pragma unroll
        for (int r = 0; r < 4; ++r) sums[s][r] = 0.0f;

    #pragma unroll
    for (int cs = 0; cs < 4; ++cs) {
        const int csub = C + cs * 16;
        #pragma unroll
        for (int s = 0; s < 4; ++s) {
            const int rowt = R + s * 16;
            if (csub == rowt) {                       // diagonal subtile
                #pragma unroll
                for (int r = 0; r < 4; ++r) {
                    float e = __builtin_amdgcn_exp2f(acc[s][cs][r]);
                    sums[s][r] += (lmod != lhi * 4 + r) ? e : 0.0f;
                }
            } else if (csub == (rowt ^ N_ROWS)) {     // positive-pair subtile
                #pragma unroll
                for (int r = 0; r < 4; ++r) {
                    if (lmod == lhi * 4 + r)
                        posv[rowt + lhi * 4 + r] = acc[s][cs][r];
                    sums[s][r] += __builtin_amdgcn_exp2f(acc[s][cs][r]);
                }
            } else {                                  // fast path
                #pragma unroll
                for (int r = 0; r < 4; ++r)
                    sums[s][r] += __builtin_amdgcn_exp2f(acc[s][cs][r]);
            }
        }
    }

    // Reduce the 16 lmod-lanes sharing each row, one atomic per row.
    #pragma unroll
    for (int s = 0; s < 4; ++s)
        #pragma unroll
        for (int r = 0; r < 4; ++r) {
            float v = sums[s][r];
            v += __shfl_xor(v, 1);
            v += __shfl_xor(v, 2);
            v += __shfl_xor(v, 4);
            v += __shfl_xor(v, 8);
            if (lmod == 0) atomicAdd(&S[R + s * 16 + lhi * 4 + r], v);
        }
}

__global__ __launch_bounds__(1024) void finalize_kernel(
        const float* __restrict__ S, const float* __restrict__ posv,
        float* __restrict__ out) {
    const int tid = threadIdx.x;
    float local = 0.0f;
    #pragma unroll
    for (int i = tid; i < TWO_N; i += 1024)
        local += logf(S[i]) - posv[i] * K_LN2;   // posv is sim*log2e/T
    #pragma unroll
    for (int m = 1; m < 64; m <<= 1) local += __shfl_xor(local, m);
    __shared__ float red[16];
    if ((tid & 63) == 0) red[tid >> 6] = local;
    __syncthreads();
    if (tid == 0) {
        float t = 0.0f;
        #pragma unroll
        for (int w = 0; w < 16; ++w) t += red[w];
        out[0] = t / (float)TWO_N;
    }
}

extern "C" void kernel_launch(void* const* d_in, const int* in_sizes, int n_in,
                              void* d_out, int out_size, void* d_ws, size_t ws_size,
                              hipStream_t stream) {
    const float* emb_i = (const float*)d_in[0];
    const float* emb_j = (const float*)d_in[1];
    float* out = (float*)d_out;

    unsigned short* z = (unsigned short*)d_ws;                    // 4 MB
    float* S    = (float*)((char*)d_ws + (size_t)TWO_N * D * 2);  // 32 KB
    float* posv = S + TWO_N;                                      // 32 KB

    normalize_kernel<<<TWO_N / 4, 256, 0, stream>>>(emb_i, emb_j, z, S);
    simexp_kernel<<<NBLOCKS, 256, 0, stream>>>(z, S, posv);
    finalize_kernel<<<1, 1024, 0, stream>>>(S, posv, out);
}